// Round 9
// baseline (213.803 us; speedup 1.0000x reference)
//
#include <hip/hip_runtime.h>
#include <hip/hip_bf16.h>
#include <hip/hip_fp16.h>

#define IN_FT  128
#define OUT_FT 32
#define APITCH 136   // f16 pitch for A tile: 272B rows, benign b128 bank pattern

#define RPB   256    // rows per bucket (bucket = row >> 8)
#define CAP   8192   // slots per bucket (mean count 4092, ~64 sigma headroom)
#define ACC_T 1024   // threads for acc
#define BIN_E 4096   // bin edges per (256-thread) block

typedef _Float16 f16x8 __attribute__((ext_vector_type(8)));
typedef __attribute__((ext_vector_type(4))) float f32x4;

union H2 { unsigned u; _Float16 h[2]; };

// ---- K1: swizzled f16 weight table + zero bptr + zero rs (multi-block) ----
// wtab[tile][kt][lane][j] = w[kt*32 + (lane>>4)*8 + j][(lane&15) + tile*16]
__global__ __launch_bounds__(256) void gcn_swz(const float* __restrict__ w,
                                               _Float16* __restrict__ wtab,
                                               int* __restrict__ bptr,
                                               int* __restrict__ rs, int nR) {
    int g = blockIdx.x * 256 + threadIdx.x;
    for (int i = g; i < nR; i += gridDim.x * 256) rs[i] = 0;
    if (blockIdx.x == 0) {
        int t = threadIdx.x;
        bptr[t] = 0;
        bptr[t + 256] = 0;
        for (int i = t; i < 2 * 4 * 64 * 8; i += 256) {
            int j    = i & 7;
            int lane = (i >> 3) & 63;
            int kt   = (i >> 9) & 3;
            int tile = i >> 11;
            int k    = kt * 32 + (lane >> 4) * 8 + j;
            int c    = (lane & 15) + tile * 16;
            wtab[i] = (_Float16)w[k * OUT_FT + c];
        }
    }
}

// ---- K2 fused: blocks [0,gb)     : sup(f16) = seq @ w via MFMA
//                blocks [gb,gb+bb) : bin edges into split ecv/ery bucket slots
//                                    + global per-row histogram rs[]
__global__ __launch_bounds__(256) void gcn_gemm_bin(const float* __restrict__ seq,
                                                    const _Float16* __restrict__ wtab,
                                                    unsigned short* __restrict__ sup,
                                                    const int* __restrict__ erow,
                                                    const int* __restrict__ ecol,
                                                    const float* __restrict__ eval,
                                                    int* __restrict__ bptr,
                                                    int* __restrict__ rs,
                                                    unsigned* __restrict__ ecv,
                                                    unsigned char* __restrict__ ery,
                                                    int n, int nE, int gb) {
    __shared__ __align__(16) _Float16 at[64 * APITCH];   // 17 KB (aliased by bin)
    const int t = threadIdx.x;

    if ((int)blockIdx.x >= gb) {
        // ---------------- bin branch (256 thr, 4096 edges) ----------------
        int* cnt = (int*)at;          // 512 ints
        int* cur = cnt + 512;         // 512 ints (4 KB total, fits in at[])
        cnt[t] = 0;
        cnt[t + 256] = 0;
        __syncthreads();

        const int cb = ((int)blockIdx.x - gb) * BIN_E;
        const int ce = min(cb + BIN_E, nE);

        // pass 1: bucket histogram (LDS) + per-row histogram (global, low
        // contention: 1.6M adds over 100K addresses)
        #pragma unroll
        for (int k = 0; k < 4; ++k) {
            int i0 = cb + (k * 256 + t) * 4;
            if (i0 + 4 <= ce) {
                int4 r4 = *(const int4*)&erow[i0];
                atomicAdd(&cnt[r4.x >> 8], 1);
                atomicAdd(&cnt[r4.y >> 8], 1);
                atomicAdd(&cnt[r4.z >> 8], 1);
                atomicAdd(&cnt[r4.w >> 8], 1);
                atomicAdd(&rs[r4.x], 1);
                atomicAdd(&rs[r4.y], 1);
                atomicAdd(&rs[r4.z], 1);
                atomicAdd(&rs[r4.w], 1);
            } else {
                for (int i = i0; i < ce; ++i) {
                    int r = erow[i];
                    atomicAdd(&cnt[r >> 8], 1);
                    atomicAdd(&rs[r], 1);
                }
            }
        }
        __syncthreads();

        // reserve one contiguous run per non-empty bucket
        if (cnt[t])       cur[t]       = atomicAdd(&bptr[t],       cnt[t]);
        if (cnt[t + 256]) cur[t + 256] = atomicAdd(&bptr[t + 256], cnt[t + 256]);
        __syncthreads();

        // pass 2: re-read chunk (L2-hot, 48 KB) + place into split arrays
        #pragma unroll
        for (int k = 0; k < 4; ++k) {
            int i0 = cb + (k * 256 + t) * 4;
            if (i0 + 4 <= ce) {
                int4   r4 = *(const int4*)&erow[i0];
                int4   c4 = *(const int4*)&ecol[i0];
                float4 v4 = *(const float4*)&eval[i0];
                int      rr[4] = {r4.x, r4.y, r4.z, r4.w};
                unsigned cq[4];
                cq[0] = ((unsigned)c4.x << 15) | (unsigned)(v4.x * 32767.f + 0.5f);
                cq[1] = ((unsigned)c4.y << 15) | (unsigned)(v4.y * 32767.f + 0.5f);
                cq[2] = ((unsigned)c4.z << 15) | (unsigned)(v4.z * 32767.f + 0.5f);
                cq[3] = ((unsigned)c4.w << 15) | (unsigned)(v4.w * 32767.f + 0.5f);
                #pragma unroll
                for (int q = 0; q < 4; ++q) {
                    int b = rr[q] >> 8;
                    int p = atomicAdd(&cur[b], 1);
                    if (p < CAP) {               // safety clamp (never expected)
                        ecv[(size_t)b * CAP + p] = cq[q];
                        ery[(size_t)b * CAP + p] = (unsigned char)(rr[q] & 255);
                    }
                }
            } else {
                for (int i = i0; i < ce; ++i) {
                    int      r = erow[i];
                    unsigned q = ((unsigned)ecol[i] << 15)
                               | (unsigned)(eval[i] * 32767.f + 0.5f);
                    int b = r >> 8;
                    int p = atomicAdd(&cur[b], 1);
                    if (p < CAP) {
                        ecv[(size_t)b * CAP + p] = q;
                        ery[(size_t)b * CAP + p] = (unsigned char)(r & 255);
                    }
                }
            }
        }
        return;
    }

    // ---------------- gemm branch (unchanged, round-8 verified) ----------------
    const int base = blockIdx.x * 64;

    for (int it = 0; it < 4; ++it) {
        int i     = it * 256 + t;
        int row_l = i >> 4;
        int c     = i & 15;
        int row   = base + row_l;
        f16x8 v = (f16x8)0;
        if (row < n) {
            const float4* p = (const float4*)(seq + (size_t)row * IN_FT + c * 8);
            float4 lo = p[0], hi = p[1];
            v[0] = (_Float16)lo.x; v[1] = (_Float16)lo.y;
            v[2] = (_Float16)lo.z; v[3] = (_Float16)lo.w;
            v[4] = (_Float16)hi.x; v[5] = (_Float16)hi.y;
            v[6] = (_Float16)hi.z; v[7] = (_Float16)hi.w;
        }
        *(f16x8*)&at[row_l * APITCH + c * 8] = v;
    }
    __syncthreads();

    const int wave = t >> 6;
    const int lane = t & 63;
    const int m    = lane & 15;
    const int quad = lane >> 4;

    const f16x8* wt = (const f16x8*)wtab;
    const int arow_l = wave * 16 + m;

    f32x4 acc0 = {0.f, 0.f, 0.f, 0.f};
    f32x4 acc1 = {0.f, 0.f, 0.f, 0.f};

    for (int kt = 0; kt < 4; ++kt) {
        f16x8 a  = *(const f16x8*)&at[arow_l * APITCH + kt * 32 + quad * 8];
        f16x8 b0 = wt[(0 * 4 + kt) * 64 + lane];
        f16x8 b1 = wt[(1 * 4 + kt) * 64 + lane];
        acc0 = __builtin_amdgcn_mfma_f32_16x16x32_f16(a, b0, acc0, 0, 0, 0);
        acc1 = __builtin_amdgcn_mfma_f32_16x16x32_f16(a, b1, acc1, 0, 0, 0);
    }

    // C/D layout: col = lane&15, row = quad*4 + reg
    for (int i = 0; i < 4; ++i) {
        int ro = base + wave * 16 + quad * 4 + i;
        if (ro < n) {
            _Float16 h0 = (_Float16)acc0[i];
            _Float16 h1 = (_Float16)acc1[i];
            sup[(size_t)ro * OUT_FT + m]      = *(unsigned short*)&h0;
            sup[(size_t)ro * OUT_FT + 16 + m] = *(unsigned short*)&h1;
        }
    }
}

// ---- K3: per-bucket sort (hist from global rs) + register-accum gather ----
// + fused relu. Block b owns rows [b*256, b*256+256). Single streaming pass
// over ery/ecv (no histogram re-read).
__global__ __launch_bounds__(ACC_T) void gcn_acc(const unsigned* __restrict__ ecv,
                                                 const unsigned char* __restrict__ ery,
                                                 const int* __restrict__ bptr,
                                                 const int* __restrict__ rs,
                                                 const unsigned* __restrict__ sup32,
                                                 float2* __restrict__ out, int n) {
    __shared__ unsigned csr[CAP];                // 32 KB row-sorted (col|val) words
    __shared__ int hist[RPB];
    __shared__ int segs[RPB];                    // inclusive scan of hist
    __shared__ int cursor[RPB];
    const int    t    = threadIdx.x;
    const int    b    = blockIdx.x;
    const int    cnt  = min(bptr[b], CAP);
    const size_t base = (size_t)b * CAP;

    // row histogram: coalesced 1 KB load from global rs (built in bin pass)
    int v = 0;
    if (t < RPB) { v = rs[b * RPB + t]; hist[t] = v; segs[t] = v; }
    __syncthreads();

    // inclusive scan of 256 row counts (first 256 threads active)
    for (int o = 1; o < RPB; o <<= 1) {
        int x = 0;
        if (t < RPB && t >= o) x = segs[t - o];
        __syncthreads();
        if (t < RPB) segs[t] += x;
        __syncthreads();
    }
    if (t < RPB) cursor[t] = segs[t] - v;        // exclusive start
    __syncthreads();

    // single placement pass: 4-wide vector loads of ery/ecv, LDS cursor sort
    for (int i0 = t * 4; i0 < cnt; i0 += ACC_T * 4) {
        if (i0 + 4 <= cnt) {
            uchar4 ry = *(const uchar4*)&ery[base + i0];
            uint4  cv = *(const uint4*) &ecv[base + i0];
            int p0 = atomicAdd(&cursor[ry.x], 1); if (p0 < CAP) csr[p0] = cv.x;
            int p1 = atomicAdd(&cursor[ry.y], 1); if (p1 < CAP) csr[p1] = cv.y;
            int p2 = atomicAdd(&cursor[ry.z], 1); if (p2 < CAP) csr[p2] = cv.z;
            int p3 = atomicAdd(&cursor[ry.w], 1); if (p3 < CAP) csr[p3] = cv.w;
        } else {
            for (int i = i0; i < cnt; ++i) {
                int p = atomicAdd(&cursor[ery[base + i]], 1);
                if (p < CAP) csr[p] = ecv[base + i];
            }
        }
    }
    __syncthreads();

    // gather: 16-lane group per row, register accumulate, direct global write
    const int g = t >> 4;                        // 64 groups
    const int j = t & 15;
    const int rbase = b * RPB;
    for (int rr = g; rr < RPB; rr += ACC_T / 16) {
        int end = min(segs[rr], CAP);
        int st  = max(end - hist[rr], 0);
        float a0 = 0.f, a1 = 0.f;
        int e = st;
        for (; e + 2 <= end; e += 2) {           // 2-edge unroll for load ILP
            unsigned c0 = csr[e], c1 = csr[e + 1];
            H2 s0; s0.u = sup32[(c0 >> 15) * 16 + j];
            H2 s1; s1.u = sup32[(c1 >> 15) * 16 + j];
            float v0 = (float)(c0 & 0x7fffu) * (1.f / 32767.f);
            float v1 = (float)(c1 & 0x7fffu) * (1.f / 32767.f);
            a0 += v0 * (float)s0.h[0] + v1 * (float)s1.h[0];
            a1 += v0 * (float)s0.h[1] + v1 * (float)s1.h[1];
        }
        if (e < end) {
            unsigned c0 = csr[e];
            H2 s0; s0.u = sup32[(c0 >> 15) * 16 + j];
            float v0 = (float)(c0 & 0x7fffu) * (1.f / 32767.f);
            a0 += v0 * (float)s0.h[0];
            a1 += v0 * (float)s0.h[1];
        }
        int row = rbase + rr;
        if (row < n) {
            float2 o;
            o.x = fmaxf(a0, 0.f);
            o.y = fmaxf(a1, 0.f);
            out[(size_t)row * 16 + j] = o;
        }
    }
}

extern "C" void kernel_launch(void* const* d_in, const int* in_sizes, int n_in,
                              void* d_out, int out_size, void* d_ws, size_t ws_size,
                              hipStream_t stream) {
    const float* seq  = (const float*)d_in[0];
    const float* w    = (const float*)d_in[1];
    const int*   erow = (const int*)d_in[2];
    const int*   ecol = (const int*)d_in[3];
    const float* eval = (const float*)d_in[4];
    float* out = (float*)d_out;

    const int n_nodes = in_sizes[0] / IN_FT;
    const int n_edges = in_sizes[2];
    const int nB      = (n_nodes + RPB - 1) / RPB;    // 391 for N=100000 (<=512)
    const int nR      = nB * RPB;                     // rounded row count

    // workspace: sup n*32 u16 (6.4 MB) | ecv nB*CAP u32 (12.8 MB)
    //          | ery nB*CAP u8 (3.2 MB) | rs nR int (0.4 MB) | bptr 512 | wtab
    unsigned short* sup  = (unsigned short*)d_ws;
    unsigned*       ecv  = (unsigned*)(sup + (size_t)n_nodes * OUT_FT);
    unsigned char*  ery  = (unsigned char*)(ecv + (size_t)nB * CAP);
    int*            rs   = (int*)(ery + (size_t)nB * CAP);
    int*            bptr = rs + nR;
    _Float16*       wtab = (_Float16*)(bptr + 512);

    // K1: weight table + zero bptr/rs
    gcn_swz<<<98, 256, 0, stream>>>(w, wtab, bptr, rs, nR);

    // K2: fused gemm (gb blocks) + edge binning (bb blocks)
    int gb = (n_nodes + 63) / 64;
    int bb = (n_edges + BIN_E - 1) / BIN_E;
    gcn_gemm_bin<<<gb + bb, 256, 0, stream>>>(seq, wtab, sup, erow, ecol, eval,
                                              bptr, rs, ecv, ery,
                                              n_nodes, n_edges, gb);

    // K3: per-bucket sort (global hist) + register-accumulate gather + relu
    gcn_acc<<<nB, ACC_T, 0, stream>>>(ecv, ery, bptr, rs, (const unsigned*)sup,
                                      (float2*)out, n_nodes);
}

// Round 10
// 153.866 us; speedup vs baseline: 1.3895x; 1.3895x over previous
//
#include <hip/hip_runtime.h>
#include <hip/hip_bf16.h>
#include <hip/hip_fp16.h>

#define IN_FT  128
#define OUT_FT 32
#define APITCH 136   // f16 pitch for A tile: 272B rows, benign b128 bank pattern

#define RPB   256    // rows per bucket (bucket = row >> 8)
#define CAP   8192   // ebin slots per bucket (mean count 4092, ~64 sigma headroom)
#define BA_T  1024   // threads for binA / acc
#define BIN_E 16384  // binA edges per block (16/thread -> 336B avg runs)

typedef _Float16 f16x8 __attribute__((ext_vector_type(8)));
typedef __attribute__((ext_vector_type(4))) float f32x4;

union H2 { unsigned u; _Float16 h[2]; };

// ---- K1: swizzled f16 weight table (8 KB) + zero bucket counters ----
// wtab[tile][kt][lane][j] = w[kt*32 + (lane>>4)*8 + j][(lane&15) + tile*16]
__global__ __launch_bounds__(256) void gcn_swz(const float* __restrict__ w,
                                               _Float16* __restrict__ wtab,
                                               int* __restrict__ bptr) {
    int t = threadIdx.x;
    bptr[t] = 0;
    bptr[t + 256] = 0;
    for (int i = t; i < 2 * 4 * 64 * 8; i += 256) {
        int j    = i & 7;
        int lane = (i >> 3) & 63;
        int kt   = (i >> 9) & 3;
        int tile = i >> 11;
        int k    = kt * 32 + (lane >> 4) * 8 + j;
        int c    = (lane & 15) + tile * 16;
        wtab[i] = (_Float16)w[k * OUT_FT + c];
    }
}

// ---- K2: sup(f16) = seq @ w via MFMA with LDS-staged coalesced A ----
__global__ __launch_bounds__(256) void gcn_gemm_mfma(const float* __restrict__ seq,
                                                     const _Float16* __restrict__ wtab,
                                                     unsigned short* __restrict__ sup,
                                                     int n) {
    __shared__ __align__(16) _Float16 at[64 * APITCH];   // 17 KB
    const int t    = threadIdx.x;
    const int base = blockIdx.x * 64;

    for (int it = 0; it < 4; ++it) {
        int i     = it * 256 + t;
        int row_l = i >> 4;
        int c     = i & 15;
        int row   = base + row_l;
        f16x8 v = (f16x8)0;
        if (row < n) {
            const float4* p = (const float4*)(seq + (size_t)row * IN_FT + c * 8);
            float4 lo = p[0], hi = p[1];
            v[0] = (_Float16)lo.x; v[1] = (_Float16)lo.y;
            v[2] = (_Float16)lo.z; v[3] = (_Float16)lo.w;
            v[4] = (_Float16)hi.x; v[5] = (_Float16)hi.y;
            v[6] = (_Float16)hi.z; v[7] = (_Float16)hi.w;
        }
        *(f16x8*)&at[row_l * APITCH + c * 8] = v;
    }
    __syncthreads();

    const int wave = t >> 6;
    const int lane = t & 63;
    const int m    = lane & 15;
    const int quad = lane >> 4;

    const f16x8* wt = (const f16x8*)wtab;
    const int arow_l = wave * 16 + m;

    f32x4 acc0 = {0.f, 0.f, 0.f, 0.f};
    f32x4 acc1 = {0.f, 0.f, 0.f, 0.f};

    for (int kt = 0; kt < 4; ++kt) {
        f16x8 a  = *(const f16x8*)&at[arow_l * APITCH + kt * 32 + quad * 8];
        f16x8 b0 = wt[(0 * 4 + kt) * 64 + lane];
        f16x8 b1 = wt[(1 * 4 + kt) * 64 + lane];
        acc0 = __builtin_amdgcn_mfma_f32_16x16x32_f16(a, b0, acc0, 0, 0, 0);
        acc1 = __builtin_amdgcn_mfma_f32_16x16x32_f16(a, b1, acc1, 0, 0, 0);
    }

    // C/D layout: col = lane&15, row = quad*4 + reg
    for (int i = 0; i < 4; ++i) {
        int ro = base + wave * 16 + quad * 4 + i;
        if (ro < n) {
            _Float16 h0 = (_Float16)acc0[i];
            _Float16 h1 = (_Float16)acc1[i];
            sup[(size_t)ro * OUT_FT + m]      = *(unsigned short*)&h0;
            sup[(size_t)ro * OUT_FT + 16 + m] = *(unsigned short*)&h1;
        }
    }
}

// ---- K3: bin edges into fixed-cap bucket slots (1024 thr, 16 edges/thread) --
// Bigger chunk -> ~42-edge (336B) runs -> ~1.2x write amplification vs 1.75x.
// ebin[b*CAP + i] = { (col<<15)|val15, row&255 } ; bptr[b] = final count
__global__ __launch_bounds__(BA_T) void gcn_binA(const int* __restrict__ erow,
                                                 const int* __restrict__ ecol,
                                                 const float* __restrict__ eval,
                                                 int* __restrict__ bptr,
                                                 uint2* __restrict__ ebin, int nE) {
    __shared__ int cnt[512];
    __shared__ int cur[512];
    const int t  = threadIdx.x;
    const int cb = blockIdx.x * BIN_E;
    if (t < 512) cnt[t] = 0;
    __syncthreads();

    int      rr[16];
    unsigned cq[16];

    // load 16 edges/thread to registers (4 x int4, coalesced) + LDS histogram
    #pragma unroll
    for (int k = 0; k < 4; ++k) {
        int i0 = cb + (k * BA_T + t) * 4;
        if (i0 + 4 <= nE) {
            int4   r4 = *(const int4*)&erow[i0];
            int4   c4 = *(const int4*)&ecol[i0];
            float4 v4 = *(const float4*)&eval[i0];
            rr[k * 4 + 0] = r4.x; rr[k * 4 + 1] = r4.y;
            rr[k * 4 + 2] = r4.z; rr[k * 4 + 3] = r4.w;
            cq[k * 4 + 0] = ((unsigned)c4.x << 15) | (unsigned)(v4.x * 32767.f + 0.5f);
            cq[k * 4 + 1] = ((unsigned)c4.y << 15) | (unsigned)(v4.y * 32767.f + 0.5f);
            cq[k * 4 + 2] = ((unsigned)c4.z << 15) | (unsigned)(v4.z * 32767.f + 0.5f);
            cq[k * 4 + 3] = ((unsigned)c4.w << 15) | (unsigned)(v4.w * 32767.f + 0.5f);
            atomicAdd(&cnt[r4.x >> 8], 1);
            atomicAdd(&cnt[r4.y >> 8], 1);
            atomicAdd(&cnt[r4.z >> 8], 1);
            atomicAdd(&cnt[r4.w >> 8], 1);
        } else {
            #pragma unroll
            for (int j = 0; j < 4; ++j) {
                int i = i0 + j;
                rr[k * 4 + j] = -1;
                if (i < nE) {
                    int r = erow[i];
                    rr[k * 4 + j] = r;
                    cq[k * 4 + j] = ((unsigned)ecol[i] << 15)
                                  | (unsigned)(eval[i] * 32767.f + 0.5f);
                    atomicAdd(&cnt[r >> 8], 1);
                }
            }
        }
    }
    __syncthreads();

    // reserve one contiguous run per non-empty bucket (392 global atomics/block)
    if (t < 512 && cnt[t]) cur[t] = atomicAdd(&bptr[t], cnt[t]);
    __syncthreads();

    // place from registers (runs land contiguously; L2 merges lines)
    #pragma unroll
    for (int k = 0; k < 16; ++k) {
        int r = rr[k];
        if (r >= 0) {
            int b = r >> 8;
            int p = atomicAdd(&cur[b], 1);
            if (p < CAP) {                       // safety clamp (never expected)
                uint2 e;
                e.x = cq[k];
                e.y = (unsigned)(r & 255);
                ebin[(size_t)b * CAP + p] = e;
            }
        }
    }
}

// ---- K4: per-bucket int-atomic row sort (LDS csr) + register-accum gather ----
// + fused relu. Block b owns rows [b*256, b*256+256).  (round-6 verified form)
__global__ __launch_bounds__(BA_T) void gcn_acc(const uint2* __restrict__ ebin,
                                                const int* __restrict__ bptr,
                                                const unsigned* __restrict__ sup32,
                                                float2* __restrict__ out, int n) {
    __shared__ unsigned csr[CAP];                // 32 KB row-sorted (col|val) words
    __shared__ int hist[RPB];
    __shared__ int segs[RPB];                    // inclusive scan of hist
    __shared__ int cursor[RPB];
    const int    t    = threadIdx.x;
    const int    b    = blockIdx.x;
    const int    cnt  = min(bptr[b], CAP);
    const size_t base = (size_t)b * CAP;

    if (t < RPB) hist[t] = 0;
    __syncthreads();

    // pass 1: row histogram (native ds_add_u32)
    for (int i = t; i < cnt; i += BA_T)
        atomicAdd(&hist[ebin[base + i].y], 1);
    __syncthreads();

    // inclusive scan of 256 row counts (first 256 threads active)
    int v = 0;
    if (t < RPB) { v = hist[t]; segs[t] = v; }
    __syncthreads();
    for (int o = 1; o < RPB; o <<= 1) {
        int x = 0;
        if (t < RPB && t >= o) x = segs[t - o];
        __syncthreads();
        if (t < RPB) segs[t] += x;
        __syncthreads();
    }
    if (t < RPB) cursor[t] = segs[t] - v;        // exclusive start
    __syncthreads();

    // pass 2: place (col|val) words row-sorted into LDS (ds_add_rtn_u32 cursor)
    for (int i = t; i < cnt; i += BA_T) {
        uint2 e = ebin[base + i];
        int   p = atomicAdd(&cursor[e.y], 1);
        csr[p] = e.x;
    }
    __syncthreads();

    // gather: 16-lane group per row, register accumulate, direct global write
    const int g = t >> 4;                        // 64 groups
    const int j = t & 15;
    const int rbase = b * RPB;
    for (int rr = g; rr < RPB; rr += BA_T / 16) {
        int end = segs[rr];
        int st  = end - hist[rr];
        float a0 = 0.f, a1 = 0.f;
        int e = st;
        for (; e + 2 <= end; e += 2) {           // 2-edge unroll for load ILP
            unsigned c0 = csr[e], c1 = csr[e + 1];
            H2 s0; s0.u = sup32[(c0 >> 15) * 16 + j];
            H2 s1; s1.u = sup32[(c1 >> 15) * 16 + j];
            float v0 = (float)(c0 & 0x7fffu) * (1.f / 32767.f);
            float v1 = (float)(c1 & 0x7fffu) * (1.f / 32767.f);
            a0 += v0 * (float)s0.h[0] + v1 * (float)s1.h[0];
            a1 += v0 * (float)s0.h[1] + v1 * (float)s1.h[1];
        }
        if (e < end) {
            unsigned c0 = csr[e];
            H2 s0; s0.u = sup32[(c0 >> 15) * 16 + j];
            float v0 = (float)(c0 & 0x7fffu) * (1.f / 32767.f);
            a0 += v0 * (float)s0.h[0];
            a1 += v0 * (float)s0.h[1];
        }
        int row = rbase + rr;
        if (row < n) {
            float2 o;
            o.x = fmaxf(a0, 0.f);
            o.y = fmaxf(a1, 0.f);
            out[(size_t)row * 16 + j] = o;
        }
    }
}

extern "C" void kernel_launch(void* const* d_in, const int* in_sizes, int n_in,
                              void* d_out, int out_size, void* d_ws, size_t ws_size,
                              hipStream_t stream) {
    const float* seq  = (const float*)d_in[0];
    const float* w    = (const float*)d_in[1];
    const int*   erow = (const int*)d_in[2];
    const int*   ecol = (const int*)d_in[3];
    const float* eval = (const float*)d_in[4];
    float* out = (float*)d_out;

    const int n_nodes = in_sizes[0] / IN_FT;
    const int n_edges = in_sizes[2];
    const int nB      = (n_nodes + RPB - 1) / RPB;    // 391 for N=100000 (<=512)

    // workspace: sup n*32 u16 (6.4 MB) | ebin nB*CAP uint2 (25.6 MB)
    //          | bptr 512 int | wtab 4096 f16
    unsigned short* sup  = (unsigned short*)d_ws;
    uint2*          ebin = (uint2*)(sup + (size_t)n_nodes * OUT_FT);
    int*            bptr = (int*)(ebin + (size_t)nB * CAP);
    _Float16*       wtab = (_Float16*)(bptr + 512);

    // K1: weight table + zero bucket counters
    gcn_swz<<<1, 256, 0, stream>>>(w, wtab, bptr);

    // K2: dense projection sup = seq @ w (f16)
    gcn_gemm_mfma<<<(n_nodes + 63) / 64, 256, 0, stream>>>(seq, wtab, sup, n_nodes);

    // K3: bucket binning (16 edges/thread, long runs)
    gcn_binA<<<(n_edges + BIN_E - 1) / BIN_E, BA_T, 0, stream>>>(erow, ecol, eval,
                                                                 bptr, ebin, n_edges);

    // K4: per-bucket int-atomic row sort + register-accumulate gather + relu
    gcn_acc<<<nB, BA_T, 0, stream>>>(ebin, bptr, (const unsigned*)sup,
                                     (float2*)out, n_nodes);
}